// Round 13
// baseline (428.940 us; speedup 1.0000x reference)
//
#include <hip/hip_runtime.h>
#include <math.h>

#define BATCH 4
#define A_TOTAL 159882
#define K_TOT 4507
#define N_WORDS 71
#define POST_N 1000

// ---- workspace offsets (bytes), all 256-aligned ----
#define OFF_SEL      0u          // int[BATCH*K_TOT]
#define OFF_SKEY     72192u      // u64[BATCH*K_TOT]
#define OFF_BOXES    216576u     // float4[BATCH*K_TOT]
#define OFF_SCORE    505088u     // float[BATCH*K_TOT]
#define OFF_MAXC     577280u     // float[BATCH]
#define OFF_BOXESS   577536u     // float4[BATCH*K_TOT] (sorted)
#define OFF_NBS      866048u     // float4[BATCH*K_TOT] (sorted, level-offset)
#define OFF_SCORES   1154560u    // float[BATCH*K_TOT] (sorted)
#define OFF_SUPINIT  1226752u    // u64[BATCH*N_WORDS]
#define OFF_MASK     1229056u    // u64[BATCH*K_TOT*N_WORDS]  (~10.2 MB)

__device__ const int d_LVL_N[5]   = {120000, 30000, 7500, 1875, 507};
__device__ const int d_LVL_OFF[5] = {0, 120000, 150000, 157500, 159375};
__device__ const int d_LVL_K[5]   = {1000, 1000, 1000, 1000, 507};
__device__ const int d_CAT_OFF[5] = {0, 1000, 2000, 3000, 4000};

// _rn intrinsics: block -ffp-contract=fast fusion so mul/add round separately (match XLA)
__device__ __forceinline__ float fadd_(float a, float b) { return __fadd_rn(a, b); }
__device__ __forceinline__ float fsub_(float a, float b) { return __fadd_rn(a, -b); }
__device__ __forceinline__ float fmul_(float a, float b) { return __fmul_rn(a, b); }

__device__ __forceinline__ unsigned flipf(float f) {
  unsigned u = __float_as_uint(f);
  return (u & 0x80000000u) ? ~u : (u | 0x80000000u);
}

__device__ __forceinline__ unsigned long long readlane64(unsigned long long v, int l) {
  unsigned lo = (unsigned)__builtin_amdgcn_readlane((int)(unsigned)(v & 0xffffffffull), l);
  unsigned hi = (unsigned)__builtin_amdgcn_readlane((int)(unsigned)(v >> 32), l);
  return ((unsigned long long)hi << 32) | (unsigned long long)lo;
}

__device__ __forceinline__ unsigned long long shflxor64(unsigned long long v, int msk) {
  unsigned lo = __shfl_xor((unsigned)(v & 0xffffffffull), msk, 64);
  unsigned hi = __shfl_xor((unsigned)(v >> 32), msk, 64);
  return ((unsigned long long)hi << 32) | (unsigned long long)lo;
}

// ---- Kernel A: per-(batch,level) exact top-k (jax.lax.top_k semantics) ----
// R13 rewrite. R12 counters: topk=137us, SQ_LDS_BANK_CONFLICT=145k (~60us),
// VALUBusy 0.8%. Conflict sources: (a) round-1 histogram atomics on ~50 hot
// exponent buckets (normal data); (b) 2048-wide u64 bitonic (stride
// conflicts x66 stages). Fixes: 4x privatized histograms (stride 2049 =
// different banks per copy); single-wave shuffle suffix-scan (replaces the
// 22-barrier block scan); bitonic REMOVED -- rank computed by counting
// (kk<=1000 iters over an LDS key array; all lanes read the same address
// per iter = broadcast, conflict-free). Set selection (threshold T + exact
// lowest-index ties) and output contract (selAnchor in rank order) are
// bit-identical to before.
#define HCOPIES 4
#define HSTRIDE 2049
#define TIE_CAP 2048

__device__ __forceinline__ void suffix_find_wave(const unsigned* hist, unsigned kcur,
                                                 unsigned* s_bucket, unsigned* s_knew,
                                                 int tid) {
  if (tid < 64) {
    const int lane = tid;
    unsigned ch[32];
    unsigned csum = 0;
#pragma unroll
    for (int j = 0; j < 32; ++j) { ch[j] = hist[lane * 32 + j]; csum += ch[j]; }
    // inclusive suffix-scan of per-lane chunk sums across the wave
    unsigned cs = csum;
    for (int off = 1; off < 64; off <<= 1) {
      unsigned nb = __shfl_down(cs, off, 64);
      cs += (lane + off < 64) ? nb : 0u;
    }
    unsigned running = cs - csum;  // suffix strictly after my chunk
#pragma unroll
    for (int j = 31; j >= 0; --j) {
      unsigned newrun = running + ch[j];
      if (newrun >= kcur && running < kcur) {
        *s_bucket = (unsigned)(lane * 32 + j);
        *s_knew = kcur - running;
      }
      running = newrun;
    }
  }
  __syncthreads();
}

__global__ __launch_bounds__(1024) void topk_kernel(const float* __restrict__ obj,
                                                    int* __restrict__ selAnchor) {
  __shared__ unsigned hist[HCOPIES * HSTRIDE];          // 32784 B
  __shared__ unsigned tieA[TIE_CAP];                    // 8192 B
  __shared__ unsigned long long selK[1024];             // 8192 B: (u<<32)|~localIdx
  __shared__ unsigned s_bucket, s_knew, s_ngt, s_ntie;
  const int tid = threadIdx.x;
  const int bid = blockIdx.x;
  const int b = bid / 5, l = bid % 5;
  const int n = d_LVL_N[l];
  const int aoff = d_LVL_OFF[l];
  const unsigned kk = (unsigned)d_LVL_K[l];
  const float* src = obj + (size_t)b * A_TOTAL + aoff;
  int* outp = selAnchor + b * K_TOT + d_CAT_OFF[l];
  const int wcopy = (tid >> 6) & (HCOPIES - 1);

  // ---- round 1: top 11 bits, 4x privatized ----
  for (int i = tid; i < HCOPIES * HSTRIDE; i += 1024) hist[i] = 0;
  __syncthreads();
  for (int i = tid; i < n; i += 1024)
    atomicAdd(&hist[wcopy * HSTRIDE + (flipf(src[i]) >> 21)], 1u);
  __syncthreads();
  for (int i = tid; i < 2048; i += 1024)
    hist[i] = hist[i] + hist[HSTRIDE + i] + hist[2 * HSTRIDE + i] + hist[3 * HSTRIDE + i];
  __syncthreads();
  suffix_find_wave(hist, kk, &s_bucket, &s_knew, tid);
  unsigned B1 = s_bucket, k2 = s_knew;
  __syncthreads();

  // ---- round 2: next 11 bits (few matching elements -> single copy) ----
  for (int i = tid; i < 2048; i += 1024) hist[i] = 0;
  __syncthreads();
  for (int i = tid; i < n; i += 1024) {
    unsigned u = flipf(src[i]);
    if ((u >> 21) == B1) atomicAdd(&hist[(u >> 10) & 2047u], 1u);
  }
  __syncthreads();
  suffix_find_wave(hist, k2, &s_bucket, &s_knew, tid);
  unsigned B2 = s_bucket, k3 = s_knew;
  __syncthreads();

  // ---- round 3: last 10 bits ----
  for (int i = tid; i < 2048; i += 1024) hist[i] = 0;
  __syncthreads();
  unsigned pfx = (B1 << 11) | B2;
  for (int i = tid; i < n; i += 1024) {
    unsigned u = flipf(src[i]);
    if ((u >> 10) == pfx) atomicAdd(&hist[u & 1023u], 1u);
  }
  __syncthreads();
  suffix_find_wave(hist, k3, &s_bucket, &s_knew, tid);
  unsigned T = (pfx << 10) | s_bucket;

  // ---- compact: u>T unordered; u==T into tie list ----
  if (tid == 0) { s_ngt = 0; s_ntie = 0; }
  __syncthreads();
  for (int i = tid; i < n; i += 1024) {
    unsigned u = flipf(src[i]);
    if (u > T) {
      unsigned p = atomicAdd(&s_ngt, 1u);
      selK[p] = ((unsigned long long)u << 32) | (unsigned)(~(unsigned)i);
    } else if (u == T) {
      unsigned q = atomicAdd(&s_ntie, 1u);
      if (q < TIE_CAP) tieA[q] = (unsigned)i;
    }
  }
  __syncthreads();
  const unsigned ngt = s_ngt, ntie = s_ntie;
  const unsigned need = kk - ngt;  // >= 1 by threshold definition; ntie >= need
  if (ntie == need) {
    // all ties selected; order handled by the rank pass
    for (unsigned q = tid; q < ntie; q += 1024)
      selK[ngt + q] = ((unsigned long long)T << 32) | (unsigned)(~tieA[q]);
  } else if (tid < 64) {
    // lowest-index tie extraction, wave 0 (typical need == 1)
    const int lane = tid;
    int prev = -1;
    for (unsigned r = 0; r < need; ++r) {
      unsigned best = 0xFFFFFFFFu;
      if (ntie <= TIE_CAP) {
        for (unsigned j = lane; j < ntie; j += 64) {
          unsigned cand = tieA[j];
          if ((int)cand > prev && cand < best) best = cand;
        }
      } else {  // pathological fallback: rescan source
        for (int j = lane; j < n; j += 64)
          if (flipf(src[j]) == T && j > prev && (unsigned)j < best) best = (unsigned)j;
      }
      for (int off = 32; off; off >>= 1) {
        unsigned o = __shfl_xor(best, off, 64);
        best = best < o ? best : o;
      }
      if (lane == 0) selK[ngt + r] = ((unsigned long long)T << 32) | (unsigned)(~best);
      prev = (int)best;
    }
  }
  __syncthreads();

  // ---- rank by counting (LDS broadcast reads, conflict-free) ----
  if (tid < (int)kk) {
    const unsigned long long mykey = selK[tid];
    unsigned r = 0;
    for (unsigned j = 0; j < kk; ++j) r += (selK[j] > mykey) ? 1u : 0u;
    unsigned myIdx = ~(unsigned)(mykey & 0xffffffffull);
    outp[r] = aoff + (int)myIdx;
  }
}

// ---- Kernel B: decode + clip + valid + sigmoid + sort key + per-image max coord ----
__global__ __launch_bounds__(512) void decode_kernel(
    const float* __restrict__ obj, const float* __restrict__ deltas,
    const float* __restrict__ anchors, const int* __restrict__ selAnchor,
    unsigned long long* __restrict__ skey, float4* __restrict__ boxes,
    float* __restrict__ score, float* __restrict__ maxc) {
  __shared__ float red[512];
  const int b = blockIdx.x;
  const int tid = threadIdx.x;
  float mymax = 0.0f;  // clipped coords >= 0
  for (int pos = tid; pos < K_TOT; pos += 512) {
    int a = selAnchor[b * K_TOT + pos];
    float4 an = ((const float4*)anchors)[a];
    float4 dl = ((const float4*)deltas)[(size_t)b * A_TOTAL + a];
    float o = obj[(size_t)b * A_TOTAL + a];
    float wa = fsub_(an.z, an.x), ha = fsub_(an.w, an.y);
    float cxa = fadd_(an.x, fmul_(0.5f, wa));
    float cya = fadd_(an.y, fmul_(0.5f, ha));
    const float CLIP = (float)4.135166556742356;  // log(1000/16)
    float dw = fminf(dl.z, CLIP), dh = fminf(dl.w, CLIP);
    float cx = fadd_(fmul_(dl.x, wa), cxa);
    float cy = fadd_(fmul_(dl.y, ha), cya);
    float w = fmul_((float)exp((double)dw), wa);
    float h = fmul_((float)exp((double)dh), ha);
    float x1 = fsub_(cx, fmul_(0.5f, w));
    float y1 = fsub_(cy, fmul_(0.5f, h));
    float x2 = fadd_(cx, fmul_(0.5f, w));
    float y2 = fadd_(cy, fmul_(0.5f, h));
    x1 = fminf(fmaxf(x1, 0.f), 800.f);
    y1 = fminf(fmaxf(y1, 0.f), 800.f);
    x2 = fminf(fmaxf(x2, 0.f), 800.f);
    y2 = fminf(fmaxf(y2, 0.f), 800.f);
    bool valid = (fsub_(x2, x1) >= 0.001f) && (fsub_(y2, y1) >= 0.001f);
    float s = (float)(1.0 / (1.0 + exp(-(double)o)));
    boxes[b * K_TOT + pos] = make_float4(x1, y1, x2, y2);
    score[b * K_TOT + pos] = s;
    float sm = valid ? s : -INFINITY;
    skey[b * K_TOT + pos] =
        ((unsigned long long)flipf(sm) << 32) | (unsigned long long)(~(unsigned)pos);
    mymax = fmaxf(mymax, fmaxf(fmaxf(x1, y1), fmaxf(x2, y2)));
  }
  red[tid] = mymax;
  __syncthreads();
  for (int s2 = 256; s2 > 0; s2 >>= 1) {
    if (tid < s2) red[tid] = fmaxf(red[tid], red[tid + s2]);
    __syncthreads();
  }
  if (tid == 0) maxc[b] = red[0];
}

// ---- Kernel S: stable sort by (score desc, pos asc); emit sorted arrays + valid bitmask ----
__global__ __launch_bounds__(1024) void sort_kernel(
    const unsigned long long* __restrict__ skey, const float4* __restrict__ boxes,
    const float* __restrict__ score, const float* __restrict__ maxc,
    float4* __restrict__ boxesS, float4* __restrict__ nbS,
    float* __restrict__ scoreS, unsigned long long* __restrict__ supInit) {
  __shared__ unsigned long long keys[8192];
  const int b = blockIdx.x;
  const int tid = threadIdx.x;
  for (int t = tid; t < 8192; t += 1024)
    keys[t] = (t < K_TOT) ? skey[b * K_TOT + t] : 0ull;
  for (unsigned kq = 2; kq <= 8192; kq <<= 1) {
    for (unsigned j = kq >> 1; j; j >>= 1) {
      __syncthreads();
      for (unsigned t = (unsigned)tid; t < 4096; t += 1024) {
        unsigned i0 = ((t & ~(j - 1)) << 1) | (t & (j - 1));
        unsigned i1 = i0 | j;
        unsigned long long a = keys[i0], c = keys[i1];
        bool up = ((i0 & kq) == 0);
        if (up ? (a < c) : (a > c)) { keys[i0] = c; keys[i1] = a; }
      }
    }
  }
  __syncthreads();
  float mc1 = fadd_(maxc[b], 1.0f);
  for (int t = tid; t < 8192; t += 1024) {
    unsigned long long key = keys[t];
    bool inr = t < K_TOT;
    unsigned pos = ~(unsigned)(key & 0xffffffffull);
    bool valid = inr && ((unsigned)(key >> 32) != 0x007FFFFFu);  // flip(-inf)
    if (inr) {
      float4 bx = boxes[b * K_TOT + pos];
      boxesS[b * K_TOT + t] = bx;
      int lvl = (int)(pos / 1000u);
      float offv = fmul_((float)lvl, mc1);
      nbS[b * K_TOT + t] = make_float4(fadd_(bx.x, offv), fadd_(bx.y, offv),
                                       fadd_(bx.z, offv), fadd_(bx.w, offv));
      scoreS[b * K_TOT + t] = score[b * K_TOT + pos];
    }
    unsigned long long bal = __ballot(valid);
    if (t < N_WORDS * 64 && (threadIdx.x & 63) == 0)
      supInit[b * N_WORDS + (t >> 6)] = ~bal;
  }
}

// ---- Kernel C: suppression bitmask (upper-triangular 64x64 tiles) ----
__global__ __launch_bounds__(64) void mask_kernel(const float4* __restrict__ nbS,
                                                  unsigned long long* __restrict__ mask) {
  const int b = blockIdx.y;
  int rem = blockIdx.x;
  int ib = 0;
  while (rem >= N_WORDS - ib) { rem -= (N_WORDS - ib); ++ib; }
  const int jb = ib + rem;
  __shared__ float4 jbox[64];
  __shared__ float jarea[64];
  const int lane = threadIdx.x;
  const int j0 = jb * 64;
  {
    int jj = j0 + lane;
    float4 bj = (jj < K_TOT) ? nbS[(size_t)b * K_TOT + jj]
                             : make_float4(-1e30f, -1e30f, -1e30f, -1e30f);
    jbox[lane] = bj;
    jarea[lane] = fmul_(fsub_(bj.z, bj.x), fsub_(bj.w, bj.y));
  }
  __syncthreads();
  const int i = ib * 64 + lane;
  if (i >= K_TOT) return;
  float4 bi = nbS[(size_t)b * K_TOT + i];
  float ai = fmul_(fsub_(bi.z, bi.x), fsub_(bi.w, bi.y));
  unsigned long long bits = 0ull;
  int jmax = K_TOT - j0; if (jmax > 64) jmax = 64;
  for (int q = 0; q < jmax; ++q) {
    int j = j0 + q;
    if (j <= i) continue;
    float4 bj = jbox[q];
    float ltx = fmaxf(bi.x, bj.x), lty = fmaxf(bi.y, bj.y);
    float rbx = fminf(bi.z, bj.z), rby = fminf(bi.w, bj.w);
    float wx = fmaxf(fsub_(rbx, ltx), 0.f), wy = fmaxf(fsub_(rby, lty), 0.f);
    float inter = fmul_(wx, wy);
    float uni = fsub_(fadd_(ai, jarea[q]), inter);
    float iou = inter / uni;  // IEEE div; 0/0=NaN -> not > thresh (matches ref)
    if (iou > 0.7f) bits |= (1ull << q);
  }
  mask[((size_t)b * K_TOT + i) * N_WORDS + jb] = bits;
}

// ---- Kernel D: sequential greedy-NMS scan, one wave per image ----
// R12 result: prefetch-all-avail + ballot emit dropped scan out of the
// top-5 (<136us). Keeping as-is this round; topk is the measured target.
__global__ __launch_bounds__(64, 1) void scan_kernel(
    const unsigned long long* __restrict__ mask,
    const unsigned long long* __restrict__ supInit,
    const float4* __restrict__ boxesS, const float* __restrict__ scoreS,
    float* __restrict__ out) {
  __shared__ unsigned short keptIdx[POST_N];
  const int b = blockIdx.x;
  const int lane = threadIdx.x;
  const unsigned long long* m = mask + (size_t)b * K_TOT * N_WORDS;
  unsigned long long supA = supInit[b * N_WORDS + lane];                       // word = lane
  unsigned long long supB = (lane < N_WORDS - 64) ? supInit[b * N_WORDS + 64 + lane] : ~0ull;
  float4* ob = (float4*)(out + (size_t)b * POST_N * 4);
  float* os = out + 4 * POST_N * 4 + (size_t)b * POST_N;
  const int lane2 = (lane + 64 < N_WORDS) ? (lane + 64) : lane;  // clamped 2nd column
  int c = 0;
  unsigned long long rw_cur = (lane < K_TOT) ? m[(size_t)lane * N_WORDS] : 0ull;
  for (int w = 0; w < N_WORDS; ++w) {
    // prefetch next group's diagonal word
    unsigned long long rw_next = 0ull;
    if (w + 1 < N_WORDS) {
      int i1 = (w + 1) * 64 + lane;
      if (i1 < K_TOT) rw_next = m[(size_t)i1 * N_WORDS + (w + 1)];
    }
    // lazy supB: fold all kept-so-far rows' cols 64..70 in, once (cold path)
    if (w == 64) {
      for (int j = 0; j < N_WORDS - 64; ++j) {
        unsigned long long acc = 0ull;
        for (int base = 0; base < c; base += 64) {
          int k2 = base + lane;
          unsigned long long v2 = 0ull;
          if (k2 < c) v2 = m[(size_t)keptIdx[k2] * N_WORDS + 64 + j];
          acc |= v2;
        }
        for (int msk = 32; msk > 0; msk >>= 1) acc |= shflxor64(acc, msk);
        if (lane == j) supB |= acc;
      }
    }
    unsigned long long v = (w < 64) ? supA : supB;
    int srcl = (w < 64) ? w : (w - 64);
    unsigned long long scur = readlane64(v, srcl);
    unsigned long long avail0 = ~scur;
    unsigned long long keptm = 0ull;

    if (w < 64) {
      // ---- fast path: prefetch ALL avail rows (col = lane) ----
      int tq[64];
      unsigned long long dA[64];
      unsigned long long av = avail0;
      if (avail0) {
#pragma unroll
        for (int q = 0; q < 64; ++q) {
          unsigned long long avq = av ? av : 1ull;       // cndmask, no branch
          tq[q] = __builtin_ctzll(avq);
          av &= av - 1ull;
          const unsigned long long* rp = m + (size_t)(w * 64 + tq[q]) * N_WORDS;
          asm volatile("global_load_dwordx2 %0, %1, off" : "=&v"(dA[q]) : "v"(rp + lane));
        }
      }
      __builtin_amdgcn_sched_barrier(0);
      // serial within-word greedy scan (overlaps the in-flight loads)
      unsigned long long avail = avail0;
      while (avail) {
        int t = __builtin_ctzll(avail);
        keptm |= (1ull << t);
        unsigned long long rw = readlane64(rw_cur, t);
        avail &= ~(rw | (1ull << t));
      }
      // parallel emit (ballot-style): rank = popcount of lower kept bits
      int nk = __popcll(keptm);
      if (keptm) {
        int pos = c + (int)__popcll(keptm & ((1ull << lane) - 1ull));
        if (((keptm >> lane) & 1ull) && pos < POST_N)
          keptIdx[pos] = (unsigned short)(w * 64 + lane);
      }
      c += nk;
      if (c >= POST_N) break;
      // drain + masked OR into supA (rule 18: sched_barrier after waitcnt)
      if (avail0) {
        asm volatile("s_waitcnt vmcnt(0)" ::: "memory");
        __builtin_amdgcn_sched_barrier(0);
        unsigned long long acc0 = 0ull;
#pragma unroll
        for (int q = 0; q < 64; ++q) {
          unsigned long long sel = ((keptm >> tq[q]) & 1ull) ? ~0ull : 0ull;
          acc0 |= dA[q] & sel;
        }
        supA |= acc0;
      }
    } else {
      // ---- tail path (w in [64,70]): original serial scan + 16-row batches
      unsigned long long avail = avail0;
      while (avail) {
        int t = __builtin_ctzll(avail);
        keptm |= (1ull << t);
        unsigned long long rw = readlane64(rw_cur, t);
        avail &= ~(rw | (1ull << t));
      }
      int nk = __popcll(keptm);
      if (keptm) {
        int pos = c + (int)__popcll(keptm & ((1ull << lane) - 1ull));
        if (((keptm >> lane) & 1ull) && pos < POST_N)
          keptIdx[pos] = (unsigned short)(w * 64 + lane);
      }
      c += nk;
      if (c >= POST_N) break;
      if (w + 1 >= N_WORDS) break;
      unsigned long long km = keptm;
      while (km != 0ull) {
        int ts[16];
        unsigned long long vm[16];
#pragma unroll
        for (int q = 0; q < 16; ++q) {
          unsigned long long kms = km ? km : 1ull;
          ts[q] = __builtin_ctzll(kms);
          vm[q] = km ? ~0ull : 0ull;
          km &= km - 1ull;
        }
        unsigned long long dA2[16], dB2[16];
#pragma unroll
        for (int q = 0; q < 16; ++q) {
          const unsigned long long* row = m + (size_t)(w * 64 + ts[q]) * N_WORDS;
          dA2[q] = row[lane];
          dB2[q] = row[lane2];
        }
        __builtin_amdgcn_sched_barrier(0);
        unsigned long long acc0 = 0ull, acc1 = 0ull;
#pragma unroll
        for (int q = 0; q < 16; ++q) {
          acc0 |= dA2[q] & vm[q];
          acc1 |= dB2[q] & vm[q];
        }
        supA |= acc0; supB |= acc1;
      }
    }
    rw_cur = rw_next;
  }
  __syncthreads();  // make LDS keptIdx writes visible to all lanes
  // parallel gather+store of the kept boxes (64 lanes, independent loads)
  for (int t2 = lane; t2 < c && t2 < POST_N; t2 += 64) {
    int i = keptIdx[t2];
    ob[t2] = boxesS[(size_t)b * K_TOT + i];
    os[t2] = scoreS[(size_t)b * K_TOT + i];
  }
  // zero-pad remaining output slots (out is poisoned each launch)
  for (int t2 = (c < POST_N ? c : POST_N) + lane; t2 < POST_N; t2 += 64) {
    ob[t2] = make_float4(0.f, 0.f, 0.f, 0.f);
    os[t2] = 0.f;
  }
}

extern "C" void kernel_launch(void* const* d_in, const int* in_sizes, int n_in,
                              void* d_out, int out_size, void* d_ws, size_t ws_size,
                              hipStream_t stream) {
  const float* obj = (const float*)d_in[0];
  const float* deltas = (const float*)d_in[1];
  const float* anchors = (const float*)d_in[2];
  float* out = (float*)d_out;
  char* ws = (char*)d_ws;

  int* selAnchor = (int*)(ws + OFF_SEL);
  unsigned long long* skey = (unsigned long long*)(ws + OFF_SKEY);
  float4* boxes = (float4*)(ws + OFF_BOXES);
  float* score = (float*)(ws + OFF_SCORE);
  float* maxc = (float*)(ws + OFF_MAXC);
  float4* boxesS = (float4*)(ws + OFF_BOXESS);
  float4* nbS = (float4*)(ws + OFF_NBS);
  float* scoreS = (float*)(ws + OFF_SCORES);
  unsigned long long* supInit = (unsigned long long*)(ws + OFF_SUPINIT);
  unsigned long long* mask = (unsigned long long*)(ws + OFF_MASK);

  hipLaunchKernelGGL(topk_kernel, dim3(BATCH * 5), dim3(1024), 0, stream, obj, selAnchor);
  hipLaunchKernelGGL(decode_kernel, dim3(BATCH), dim3(512), 0, stream,
                     obj, deltas, anchors, selAnchor, skey, boxes, score, maxc);
  hipLaunchKernelGGL(sort_kernel, dim3(BATCH), dim3(1024), 0, stream,
                     skey, boxes, score, maxc, boxesS, nbS, scoreS, supInit);
  hipLaunchKernelGGL(mask_kernel, dim3(N_WORDS * (N_WORDS + 1) / 2, BATCH), dim3(64), 0, stream,
                     nbS, mask);
  hipLaunchKernelGGL(scan_kernel, dim3(BATCH), dim3(64), 0, stream,
                     mask, supInit, boxesS, scoreS, out);
}